// Round 5
// baseline (178.935 us; speedup 1.0000x reference)
//
#include <hip/hip_runtime.h>
#include <stdint.h>

// Problem constants (fixed by the reference file)
#define T_TOTAL  4194304          // B*K*N = 8*4*131072
#define NEG_IDLE (-100000000.0f)
#define NEG_FILL (-1000.0f)

#define BLOCK   256
#define EPT     8
#define EPB     (BLOCK * EPT)       // 2048 elements per block
#define NBLOCKS (T_TOTAL / EPB)     // 2048 blocks
// N = 131072 = 64 * 2048 -> each block has one uniform (b,k): bk = blk >> 6

// LDS pad-swizzle for the output-transpose pass only (stride-24 writes would
// be 16-way bank conflicts). The staging/gather pass uses LINEAR addressing:
// global_load_lds requires a linear dest (m104), and the stride-3 gather read
// is <=2-way bank aliasing = free (m136).
#define SWZ(d) ((d) + ((d) >> 5))

typedef unsigned int u32x4 __attribute__((ext_vector_type(4)));
typedef float        f32x4 __attribute__((ext_vector_type(4)));

// 8 consecutive int32 bool elements -> 8-bit mask (jnp bool arrives as int32)
__device__ __forceinline__ unsigned decode8_i32(const u32x4 a, const u32x4 b) {
    return (a.x ? 1u : 0u) | (a.y ? 2u : 0u) | (a.z ? 4u : 0u) | (a.w ? 8u : 0u)
         | (b.x ? 16u : 0u) | (b.y ? 32u : 0u) | (b.z ? 64u : 0u) | (b.w ? 128u : 0u);
}

__device__ __forceinline__ f32x4 mk4(float a, float b, float c, float d) {
    f32x4 v; v.x = a; v.y = b; v.z = c; v.w = d; return v;
}

// async global->LDS, 16 B per lane; LDS dest = wave-uniform base + lane*16
__device__ __forceinline__ void gl2lds16(const float* g, float* l) {
    __builtin_amdgcn_global_load_lds(
        (const __attribute__((address_space(1))) void*)g,
        (__attribute__((address_space(3))) void*)l, 16, 0, 0);
}

// ---------------------------------------------------------------------------
// Kernel 1: per-block mask popcounts + bit-repack (1 barrier). Masks are
// read-once 32 MB -> nontemporal.
// ---------------------------------------------------------------------------
__global__ __launch_bounds__(BLOCK) void reduce_pack_kernel(
    const u32x4* __restrict__ ms,
    const u32x4* __restrict__ ma,
    unsigned long long* __restrict__ sums,
    unsigned short* __restrict__ packed)
{
    const int blk  = blockIdx.x;
    const int tid  = threadIdx.x;
    const int lane = tid & 63;
    const int wave = tid >> 6;
    const size_t e = (size_t)blk * EPB + (size_t)tid * EPT;

    const u32x4* ps = ms + (e >> 2);
    const u32x4* pa = ma + (e >> 2);
    const u32x4 s0 = __builtin_nontemporal_load(ps);
    const u32x4 s1 = __builtin_nontemporal_load(ps + 1);
    const u32x4 a0 = __builtin_nontemporal_load(pa);
    const u32x4 a1 = __builtin_nontemporal_load(pa + 1);
    const unsigned bits_s = decode8_i32(s0, s1);
    const unsigned bits_a = decode8_i32(a0, a1);
    packed[blk * BLOCK + tid] = (unsigned short)(bits_s | (bits_a << 8));

    unsigned long long v =
        ((unsigned long long)(unsigned)__popc(bits_a) << 32) | (unsigned)__popc(bits_s);
    #pragma unroll
    for (int d = 32; d; d >>= 1) v += __shfl_down(v, d, 64);

    __shared__ unsigned long long w[BLOCK / 64];
    if (lane == 0) w[wave] = v;
    __syncthreads();
    if (tid == 0) sums[blk] = w[0] + w[1] + w[2] + w[3];
}

// ---------------------------------------------------------------------------
// Kernel 2: block prefix + async-LDS rgb staging + LDS gather + transpose out.
//  - rgb staged via global_load_lds (no VGPR round-trip, 1 KB/wave-instr),
//    linear LDS layout, 16B-aligned global base (delta fixup 0..3 dwords);
//  - ls/la gathered direct from global (4 KB dense ranges), issued BEFORE
//    staging so all VMEM shares one in-flight window;
//  - LDS = 25.4 KB -> 6 blocks/CU (was 4 with the ls buffer).
// ---------------------------------------------------------------------------
__global__ __launch_bounds__(BLOCK) void scatter_kernel(
    const float* __restrict__ rgb,
    const float* __restrict__ ls,
    const float* __restrict__ la,
    const unsigned long long* __restrict__ sums,
    const unsigned short* __restrict__ packed,
    const float* __restrict__ idle_states,
    float* __restrict__ out)
{
    // linear staging needs <= 3*2048+3+2 = 6149; SWZ transpose needs 6335
    __shared__ float rgbb[6340];                 // 25360 B, reused for output
    __shared__ unsigned long long wtot[BLOCK / 64];
    __shared__ unsigned long long wpre[BLOCK / 64];

    const int blk  = blockIdx.x;
    const int tid  = threadIdx.x;
    const int lane = tid & 63;
    const int wave = tid >> 6;

    // ---- masks + own-block totals ----
    const unsigned p = packed[blk * BLOCK + tid];
    const unsigned bits_s = p & 0xffu;
    const unsigned bits_a = p >> 8;
    const int cnt_s = (int)(unsigned)(sums[blk] & 0xffffffffu);

    // ---- block prefix: thread t covers sums[8t..8t+8) (16 KB, L2-hot) ----
    unsigned long long acc = 0;
    {
        const ulonglong2* s2 = (const ulonglong2*)sums;
        const int i0 = tid * 8;
        #pragma unroll
        for (int q = 0; q < 4; ++q) {
            const ulonglong2 v = s2[tid * 4 + q];
            const int i = i0 + 2 * q;
            acc += (i     < blk) ? v.x : 0ull;
            acc += (i + 1 < blk) ? v.y : 0ull;
        }
        #pragma unroll
        for (int d = 32; d; d >>= 1) acc += __shfl_down(acc, d, 64);
    }

    // ---- wave-level inclusive scan of packed (air<<32 | surf) counts ----
    const unsigned long long pk =
        ((unsigned long long)(unsigned)__popc(bits_a) << 32) | (unsigned)__popc(bits_s);
    unsigned long long incl = pk;
    #pragma unroll
    for (int d = 1; d < 64; d <<= 1) {
        unsigned long long t = __shfl_up(incl, d, 64);
        if (lane >= d) incl += t;
    }
    unsigned long long excl = incl - pk;

    if (lane == 63) wtot[wave] = incl;
    if (lane == 0)  wpre[wave] = acc;
    __syncthreads();
    #pragma unroll
    for (int w = 0; w < BLOCK / 64; ++w)
        if (w < wave) excl += wtot[w];
    const unsigned long long pre = wpre[0] + wpre[1] + wpre[2] + wpre[3];
    const unsigned long long st  = pre + excl;   // low32 can't carry into high32

    const int start_s = (int)(unsigned)(pre & 0xffffffffu);   // block's surf base
    const int idx_a0  = (int)(st >> 32);                      // global air idx
    const int loc_s0  = (int)(unsigned)(st & 0xffffffffu) - start_s; // in-block

    // ---- per-element indices (local for surf, global for air) ----
    int ls_[EPT], ia_[EPT];
    #pragma unroll
    for (int j = 0; j < EPT; ++j) {
        ls_[j] = loc_s0 + __popc(bits_s & ((1u << j) - 1u));
        ia_[j] = idx_a0 + __popc(bits_a & ((1u << j) - 1u));
    }

    // ---- issue ls/la gathers first: dense 4 KB ranges, latency hides under
    //      the async staging below (one shared in-flight VMEM window) ----
    float sv[EPT], av[EPT];
    #pragma unroll
    for (int j = 0; j < EPT; ++j) {
        sv[j] = __builtin_nontemporal_load(ls + (start_s + ls_[j]));
        av[j] = __builtin_nontemporal_load(la + ia_[j]);
    }

    // ---- async rgb staging: global_load_lds, 1 KB per wave-instruction ----
    const int start3  = start_s * 3;
    const int start3a = start3 & ~3;             // 16B-aligned dword base
    const int delta   = start3 - start3a;        // 0..3 dword fixup
    const int c3p     = cnt_s * 3 + delta;       // dwords to stage (<=6147)
    const float* gbase = rgb + start3a;
    #pragma unroll
    for (int q = 0; q < 6; ++q) {
        const int off = (q * 4 + wave) * 256;    // interleaved -> balanced waves
        if (off < c3p)                           // wave-uniform predicate
            gl2lds16(gbase + off + lane * 4, &rgbb[off]);
    }
    __syncthreads();                             // drains vmcnt incl. staging

    // ---- LDS gathers, linear, stride-3 across lanes (<=2-way, free) ----
    float r[3 * EPT];
    #pragma unroll
    for (int j = 0; j < EPT; ++j) {
        const int b = 3 * ls_[j] + delta;        // <= 6149, in-bounds
        r[3 * j + 0] = rgbb[b];
        r[3 * j + 1] = rgbb[b + 1];
        r[3 * j + 2] = rgbb[b + 2];
    }
    __syncthreads();   // all rgbb reads done; buffer reused for output below

    // ---- select/scale ----
    const float idle      = idle_states[blk >> 6];   // uniform per block
    const float scale     = 1.0f - idle;
    const float idle_term = idle * NEG_IDLE;
    #pragma unroll
    for (int j = 0; j < EPT; ++j) {
        const bool bs = (bits_s >> j) & 1u;
        const bool ba = (bits_a >> j) & 1u;
        r[3 * j + 0] = bs ? r[3 * j + 0] * scale : 0.0f;
        r[3 * j + 1] = bs ? r[3 * j + 1] * scale : 0.0f;
        r[3 * j + 2] = bs ? r[3 * j + 2] * scale : 0.0f;
        sv[j] = bs ? (sv[j] * scale + idle_term) : NEG_FILL;
        av[j] = ba ? (av[j] * scale + idle_term) : NEG_FILL;
    }

    // ---- ls/la stores direct (32B/thread, nontemporal) ----
    const size_t base = (size_t)blk * EPB + (size_t)tid * EPT;
    {
        f32x4* pls = (f32x4*)(out + (size_t)3 * T_TOTAL + base);
        __builtin_nontemporal_store(mk4(sv[0], sv[1], sv[2], sv[3]), pls);
        __builtin_nontemporal_store(mk4(sv[4], sv[5], sv[6], sv[7]), pls + 1);
        f32x4* pla = (f32x4*)(out + (size_t)4 * T_TOTAL + base);
        __builtin_nontemporal_store(mk4(av[0], av[1], av[2], av[3]), pla);
        __builtin_nontemporal_store(mk4(av[4], av[5], av[6], av[7]), pla + 1);
    }

    // ---- rgb output transpose: regs -> LDS (SWZ) -> coalesced float4 ----
    #pragma unroll
    for (int j = 0; j < 3 * EPT; ++j) {
        const int e = tid * 24 + j;              // this thread's 24 out dwords
        rgbb[SWZ(e)] = r[j];
    }
    __syncthreads();
    float* out_rgb = out + (size_t)blk * (EPB * 3);
    #pragma unroll
    for (int i = 0; i < 6; ++i) {
        const int g = tid * 4 + 1024 * i;        // lane-consecutive 16B chunks
        const f32x4 v = mk4(rgbb[SWZ(g)], rgbb[SWZ(g + 1)],
                            rgbb[SWZ(g + 2)], rgbb[SWZ(g + 3)]);
        __builtin_nontemporal_store(v, (f32x4*)(out_rgb + g));
    }
}

// ---------------------------------------------------------------------------
extern "C" void kernel_launch(void* const* d_in, const int* in_sizes, int n_in,
                              void* d_out, int out_size, void* d_ws, size_t ws_size,
                              hipStream_t stream) {
    const float* rgb  = (const float*)d_in[0];
    const float* ls   = (const float*)d_in[1];
    const float* la   = (const float*)d_in[2];
    const u32x4* ms   = (const u32x4*)d_in[3];   // jnp bool -> int32 on device
    const u32x4* ma   = (const u32x4*)d_in[4];
    const float* idle = (const float*)d_in[5];
    float* out = (float*)d_out;

    unsigned long long* sums   = (unsigned long long*)d_ws;
    unsigned short*     packed = (unsigned short*)((uint8_t*)d_ws + NBLOCKS * sizeof(unsigned long long));

    reduce_pack_kernel<<<NBLOCKS, BLOCK, 0, stream>>>(ms, ma, sums, packed);
    scatter_kernel<<<NBLOCKS, BLOCK, 0, stream>>>(rgb, ls, la, sums, packed,
                                                  idle, out);
}